// Round 7
// baseline (453.264 us; speedup 1.0000x reference)
//
#include <hip/hip_runtime.h>
#include <hip/hip_bf16.h>

typedef __bf16 bf16x8_t __attribute__((ext_vector_type(8)));
typedef float f32x4_t __attribute__((ext_vector_type(4)));

__device__ __forceinline__ float bits2f(unsigned int u) {
    union { unsigned int u; float f; } c; c.u = u; return c.f;
}
__device__ __forceinline__ unsigned short f2bf_bits(float f) {
    __hip_bfloat16 h = __float2bfloat16(f);
    return __builtin_bit_cast(unsigned short, h);
}

// ---------------- sentinel (ws too small) ----------------
__global__ void sentinel_fill(float* __restrict__ out, int n) {
    int i = blockIdx.x * blockDim.x + threadIdx.x;
    if (i < n) out[i] = 100.0f;
}

// ---------------- edge_index dtype detection (int64 vs int32) ----------------
__global__ void detect_ei(const unsigned int* __restrict__ ei, int* __restrict__ flags) {
    int lane = threadIdx.x;
    int cz = 0;
    #pragma unroll
    for (int j = 0; j < 4; ++j) {
        int idx = lane * 4 + j;          // 0..255
        cz += (ei[2 * idx + 1] == 0u);   // odd words zero => int64 storage
    }
    #pragma unroll
    for (int off = 32; off; off >>= 1) cz += __shfl_down(cz, off);
    if (lane == 0) flags[0] = (cz > 200);
}

// ---------------- CSR build ----------------

__global__ void count_edges_dual(const int* __restrict__ ei, int* __restrict__ cnt,
                                 int E, int M, const int* __restrict__ flags) {
    int e = blockIdx.x * blockDim.x + threadIdx.x;
    if (e < E) {
        int c = flags[0] ? ei[2 * E + 2 * e] : ei[E + e];
        if ((unsigned)c < (unsigned)M) atomicAdd(&cnt[c], 1);
    }
}

// phase 1: per-256-block exclusive scan + block sums
__global__ void scan_blocks(const int* __restrict__ cnt, int* __restrict__ excl,
                            int* __restrict__ bsum, int n) {
    int tid = threadIdx.x;
    int i = blockIdx.x * 256 + tid;
    int lane = tid & 63, wv = tid >> 6;
    __shared__ int ws[4];
    int v = (i < n) ? cnt[i] : 0;
    int s = v;
    #pragma unroll
    for (int off = 1; off < 64; off <<= 1) {
        int t = __shfl_up(s, off);
        if (lane >= off) s += t;
    }
    if (lane == 63) ws[wv] = s;
    __syncthreads();
    if (tid == 0) { int a = 0; for (int q = 0; q < 4; ++q) { int t = ws[q]; ws[q] = a; a += t; } }
    __syncthreads();
    int ex = s - v + ws[wv];
    if (i < n) excl[i] = ex;
    if (tid == 255) bsum[blockIdx.x] = ex + v;
}

// phase 2: single-block scan of block sums (+ writes colptr[n] total)
__global__ void scan_bsums(const int* __restrict__ bsum, int* __restrict__ boff,
                           int nb, int* __restrict__ colptr, int n) {
    int tid = threadIdx.x, lane = tid & 63, wv = tid >> 6;
    __shared__ int ws[4];
    __shared__ int carry;
    if (tid == 0) carry = 0;
    __syncthreads();
    for (int base = 0; base < nb; base += 256) {
        int i = base + tid;
        int v = (i < nb) ? bsum[i] : 0;
        int s = v;
        #pragma unroll
        for (int off = 1; off < 64; off <<= 1) {
            int t = __shfl_up(s, off);
            if (lane >= off) s += t;
        }
        if (lane == 63) ws[wv] = s;
        __syncthreads();
        if (tid == 0) { int a = carry; for (int q = 0; q < 4; ++q) { int t = ws[q]; ws[q] = a; a += t; } carry = a; }
        __syncthreads();
        int ex = s - v + ws[wv];
        if (i < nb) boff[i] = ex;
        __syncthreads();
    }
    if (tid == 0) colptr[n] = carry;
}

// phase 3: add block offsets; also compute dinv
__global__ void scan_add_dinv(const int* __restrict__ excl, const int* __restrict__ boff,
                              const int* __restrict__ cnt, int* __restrict__ colptr,
                              int* __restrict__ cursor, float* __restrict__ dinv, int n) {
    int i = blockIdx.x * 256 + threadIdx.x;
    if (i < n) {
        int v = excl[i] + boff[blockIdx.x];
        colptr[i] = v;
        cursor[i] = v;
        dinv[i] = rsqrtf((float)cnt[i] + 1.0f);
    }
}

__global__ void fill_csr_dual(const int* __restrict__ ei, int* __restrict__ cursor,
                              int* __restrict__ esrc, int E, int M,
                              const int* __restrict__ flags) {
    int e = blockIdx.x * blockDim.x + threadIdx.x;
    if (e < E) {
        int r, c;
        if (flags[0]) { r = ei[2 * e]; c = ei[2 * E + 2 * e]; }
        else          { r = ei[e];     c = ei[E + e]; }
        if ((unsigned)c < (unsigned)M && (unsigned)r < (unsigned)M) {
            int p = atomicAdd(&cursor[c], 1);
            if ((unsigned)p < (unsigned)E) esrc[p] = r;
        }
    }
}

// ---------------- fused weight transposes f32 -> bf16 (W^T layout) ----------------
__global__ void transpose_all(const float* __restrict__ W1, const float* __restrict__ W2,
                              const float* __restrict__ W3,
                              unsigned short* __restrict__ Wt1, unsigned short* __restrict__ Wt2,
                              unsigned short* __restrict__ Wt3) {
    int i = blockIdx.x * 256 + threadIdx.x;
    if (i < 32768) {                       // W1: 128x256
        int k = i >> 8, n = i & 255;
        Wt1[n * 128 + k] = f2bf_bits(W1[i]);
    } else if (i < 32768 + 65536) {        // W2: 256x256
        int j = i - 32768;
        int k = j >> 8, n = j & 255;
        Wt2[n * 256 + k] = f2bf_bits(W2[j]);
    } else if (i < 114688) {               // W3: 256x64
        int j = i - 98304;
        int k = j >> 6, n = j & 63;
        Wt3[n * 256 + k] = f2bf_bits(W3[j]);
    }
}

// ---------------- x pre-scale: xs[i][k] = bf16(x[i][k] * dinv[i]) ----------------
__global__ void prescale_x(const float* __restrict__ x, const float* __restrict__ dinv,
                           unsigned short* __restrict__ xs, int total) {
    int i = blockIdx.x * 256 + threadIdx.x;
    if (i < total) {
        int row = i >> 7;   // K=128
        xs[i] = f2bf_bits(x[i] * dinv[row]);
    }
}

// ---------------- tiled GEMM (bf16 MFMA) ----------------
// EPI=0: Y = dinv[m] * (A·B)   (bf16 out)
// EPI=1: Y = sigmoid(A·B + bias[n]) (bf16 out)
template<int K, int BN, int NTOT, bool AF32, int EPI>
__global__ __launch_bounds__(256) void gemm_tile(
    const void* __restrict__ A,
    const unsigned short* __restrict__ Bt,
    const float* __restrict__ dinv,
    const float* __restrict__ bias,
    __hip_bfloat16* __restrict__ Y,
    int M)
{
    constexpr int KP = K + 8;
    constexpr int NT = BN / 2 / 16;   // n-tiles per wave
    __shared__ unsigned short Bs[BN * KP];

    const int tid  = threadIdx.x;
    const int lane = tid & 63;
    const int wave = tid >> 6;        // 0..3
    const int wm   = wave >> 1;       // 0..1  row group
    const int wn   = wave & 1;        // 0..1  col group
    const int quad = lane >> 4;       // 0..3
    const int l16  = lane & 15;
    const int n0   = blockIdx.y * BN;

    constexpr int CH = BN * K / 8;    // 16B chunks
    for (int idx = tid; idx < CH; idx += 256) {
        int n  = idx / (K / 8);
        int k8 = idx - n * (K / 8);
        uint4 v = *(const uint4*)(Bt + (size_t)(n0 + n) * K + k8 * 8);
        *(uint4*)&Bs[n * KP + k8 * 8] = v;
    }
    __syncthreads();

    int mrow[4];
#pragma unroll
    for (int mt = 0; mt < 4; ++mt) {
        int r = blockIdx.x * 128 + wm * 64 + mt * 16 + l16;
        mrow[mt] = (r < M) ? r : (M - 1);
    }

    f32x4_t acc[4][NT];
#pragma unroll
    for (int mt = 0; mt < 4; ++mt)
#pragma unroll
        for (int t = 0; t < NT; ++t) acc[mt][t] = (f32x4_t){0.f, 0.f, 0.f, 0.f};

    const unsigned short* BsW = &Bs[(wn * (BN / 2)) * KP];

#pragma unroll
    for (int kc = 0; kc < K; kc += 32) {
        bf16x8_t a[4], b[NT];
#pragma unroll
        for (int mt = 0; mt < 4; ++mt) {
            if constexpr (AF32) {
                const float* Af = (const float*)A + (size_t)mrow[mt] * K + kc + quad * 8;
                float4 f0 = *(const float4*)(Af);
                float4 f1 = *(const float4*)(Af + 4);
                a[mt] = (bf16x8_t){(__bf16)f0.x, (__bf16)f0.y, (__bf16)f0.z, (__bf16)f0.w,
                                   (__bf16)f1.x, (__bf16)f1.y, (__bf16)f1.z, (__bf16)f1.w};
            } else {
                a[mt] = *(const bf16x8_t*)((const __bf16*)A + (size_t)mrow[mt] * K + kc + quad * 8);
            }
        }
#pragma unroll
        for (int t = 0; t < NT; ++t) {
            b[t] = *(const bf16x8_t*)&BsW[(t * 16 + l16) * KP + kc + quad * 8];
        }
#pragma unroll
        for (int mt = 0; mt < 4; ++mt)
#pragma unroll
            for (int t = 0; t < NT; ++t)
                acc[mt][t] = __builtin_amdgcn_mfma_f32_16x16x32_bf16(a[mt], b[t], acc[mt][t], 0, 0, 0);
    }

    float bv[NT];
    if constexpr (EPI == 1) {
#pragma unroll
        for (int t = 0; t < NT; ++t)
            bv[t] = bias[n0 + wn * (BN / 2) + t * 16 + l16];
    }

#pragma unroll
    for (int mt = 0; mt < 4; ++mt) {
        int rowbase = blockIdx.x * 128 + wm * 64 + mt * 16 + quad * 4;
#pragma unroll
        for (int r = 0; r < 4; ++r) {
            int rrow = rowbase + r;
            if (rrow < M) {
                if constexpr (EPI == 0) {
                    float dv = dinv[rrow];
#pragma unroll
                    for (int t = 0; t < NT; ++t) {
                        int ccol = n0 + wn * (BN / 2) + t * 16 + l16;
                        Y[(size_t)rrow * NTOT + ccol] = __float2bfloat16(acc[mt][t][r] * dv);
                    }
                } else {
#pragma unroll
                    for (int t = 0; t < NT; ++t) {
                        int ccol = n0 + wn * (BN / 2) + t * 16 + l16;
                        float o = acc[mt][t][r] + bv[t];
                        o = 1.f / (1.f + __expf(-o));
                        Y[(size_t)rrow * NTOT + ccol] = __float2bfloat16(o);
                    }
                }
            }
        }
    }
}

// ---------------- Sliced aggregation ----------------
// out[i][sl0..sl0+64) = post(dinv[i]*(sum_{src} y[src] + y[i]) [+ bias]) per 64-ch slice.
// 8 lanes per edge row (16B each), 8 edges in flight per wave; grid.y = C/64 slices.
template<int C, bool SIG, bool OUTF32, bool HASB>
__global__ __launch_bounds__(256) void aggregate_slice(
    const unsigned short* __restrict__ Y,
    const int* __restrict__ colptr,
    const int* __restrict__ esrc,
    const float* __restrict__ dinv,
    const float* __restrict__ bias,
    void* __restrict__ H,
    int M, int Etot)
{
    const int lane = threadIdx.x & 63;
    const int wave = threadIdx.x >> 6;
    const int l = lane & 7;        // 16B sub-offset within slice
    const int g = lane >> 3;       // 0..7 edge group
    const int sl0 = blockIdx.y * 64;
    int node = blockIdx.x * 4 + wave;
    if (node >= M) return;

    int s = colptr[node];
    int e = colptr[node + 1];
    if (s < 0) s = 0;
    if (e > Etot) e = Etot;
    if (e < s) e = s;

    float acc[8];
    #pragma unroll
    for (int k = 0; k < 8; ++k) acc[k] = 0.f;

    for (int base = s; base < e; base += 64) {
        int n = e - base; if (n > 64) n = 64;
        int my = (lane < n) ? esrc[base + lane] : 0;
        if ((unsigned)my >= (unsigned)M) my = 0;
        for (int j = 0; j < n; j += 8) {
            int idx = j + g;
            int src = __shfl(my, idx);
            if (idx < n) {
                uint4 u = *(const uint4*)(Y + (size_t)src * C + sl0 + l * 8);
                acc[0] += bits2f(u.x << 16);
                acc[1] += bits2f(u.x & 0xffff0000u);
                acc[2] += bits2f(u.y << 16);
                acc[3] += bits2f(u.y & 0xffff0000u);
                acc[4] += bits2f(u.z << 16);
                acc[5] += bits2f(u.z & 0xffff0000u);
                acc[6] += bits2f(u.w << 16);
                acc[7] += bits2f(u.w & 0xffff0000u);
            }
        }
    }
    // self-loop term (group 0 only)
    if (g == 0) {
        uint4 u = *(const uint4*)(Y + (size_t)node * C + sl0 + l * 8);
        acc[0] += bits2f(u.x << 16);
        acc[1] += bits2f(u.x & 0xffff0000u);
        acc[2] += bits2f(u.y << 16);
        acc[3] += bits2f(u.y & 0xffff0000u);
        acc[4] += bits2f(u.z << 16);
        acc[5] += bits2f(u.z & 0xffff0000u);
        acc[6] += bits2f(u.w << 16);
        acc[7] += bits2f(u.w & 0xffff0000u);
    }
    // cross-group reduction (8 groups)
    #pragma unroll
    for (int off = 8; off < 64; off <<= 1) {
        #pragma unroll
        for (int k = 0; k < 8; ++k) acc[k] += __shfl_xor(acc[k], off);
    }

    if (g == 0) {   // lanes 0..7 hold channels sl0 + l*8 .. +8
        float dv = dinv[node];
        float o[8];
        #pragma unroll
        for (int k = 0; k < 8; ++k) {
            o[k] = acc[k] * dv;
            if (HASB) o[k] += bias[sl0 + l * 8 + k];
            if (SIG) o[k] = 1.f / (1.f + __expf(-o[k]));
        }
        if constexpr (OUTF32) {
            float* Hp = (float*)H + (size_t)node * C + sl0 + l * 8;
            *(float4*)Hp       = (float4){o[0], o[1], o[2], o[3]};
            *(float4*)(Hp + 4) = (float4){o[4], o[5], o[6], o[7]};
        } else {
            uint4 st;
            st.x = (unsigned int)f2bf_bits(o[0]) | ((unsigned int)f2bf_bits(o[1]) << 16);
            st.y = (unsigned int)f2bf_bits(o[2]) | ((unsigned int)f2bf_bits(o[3]) << 16);
            st.z = (unsigned int)f2bf_bits(o[4]) | ((unsigned int)f2bf_bits(o[5]) << 16);
            st.w = (unsigned int)f2bf_bits(o[6]) | ((unsigned int)f2bf_bits(o[7]) << 16);
            *(uint4*)((unsigned short*)H + (size_t)node * C + sl0 + l * 8) = st;
        }
    }
}

// ---------------- launch ----------------

extern "C" void kernel_launch(void* const* d_in, const int* in_sizes, int n_in,
                              void* d_out, int out_size, void* d_ws, size_t ws_size,
                              hipStream_t stream)
{
    int iEI = 2, iW1 = 3, iB1 = 4, iW2 = 5, iB2 = 6, iW3 = 7, iB3 = 8;
    if (n_in == 8) { iEI = 1; iW1 = 2; iB1 = 3; iW2 = 4; iB2 = 5; iW3 = 6; iB3 = 7; }

    const float* x  = (const float*)d_in[0];
    const int* ei   = (const int*)d_in[iEI];
    const float* W1 = (const float*)d_in[iW1];
    const float* b1 = (const float*)d_in[iB1];
    const float* W2 = (const float*)d_in[iW2];
    const float* b2 = (const float*)d_in[iB2];
    const float* W3 = (const float*)d_in[iW3];
    const float* b3 = (const float*)d_in[iB3];

    const int M = in_sizes[0] / 128;     // 50000
    const int E = in_sizes[iEI] / 2;     // 800000
    const int NB = (M + 255) / 256;      // scan blocks

    auto rnd = [](size_t b) { return (b + 255) & ~(size_t)255; };
    size_t needed = rnd(64 * 4)                          // flags
                  + rnd((size_t)M * 4) * 2               // dinv, cnt
                  + rnd((size_t)(M + 1) * 4)             // colptr
                  + rnd((size_t)M * 4)                   // cursor
                  + rnd((size_t)M * 4)                   // excl
                  + rnd((size_t)(NB + 1) * 4) * 2        // bsum, boff
                  + rnd((size_t)E * 4)                   // esrc
                  + rnd((size_t)256 * 128 * 2)           // Wt1
                  + rnd((size_t)256 * 256 * 2)           // Wt2
                  + rnd((size_t)64 * 256 * 2)            // Wt3
                  + rnd((size_t)M * 256 * 2) * 2;        // ybuf, hbuf
    if (ws_size < needed) {
        sentinel_fill<<<(out_size + 255) / 256, 256, 0, stream>>>((float*)d_out, out_size);
        return;
    }

    char* p = (char*)d_ws;
    auto alloc = [&](size_t bytes) {
        char* r = p;
        p += (bytes + 255) & ~(size_t)255;
        return r;
    };
    int* flags  = (int*)alloc(64 * 4);
    float* dinv = (float*)alloc((size_t)M * 4);
    int* cnt    = (int*)alloc((size_t)M * 4);
    int* colptr = (int*)alloc((size_t)(M + 1) * 4);
    int* cursor = (int*)alloc((size_t)M * 4);
    int* excl   = (int*)alloc((size_t)M * 4);
    int* bsum   = (int*)alloc((size_t)(NB + 1) * 4);
    int* boff   = (int*)alloc((size_t)(NB + 1) * 4);
    int* esrc   = (int*)alloc((size_t)E * 4);
    unsigned short* Wt1 = (unsigned short*)alloc((size_t)256 * 128 * 2);
    unsigned short* Wt2 = (unsigned short*)alloc((size_t)256 * 256 * 2);
    unsigned short* Wt3 = (unsigned short*)alloc((size_t)64 * 256 * 2);
    __hip_bfloat16* ybuf = (__hip_bfloat16*)alloc((size_t)M * 256 * 2);
    __hip_bfloat16* hbuf = (__hip_bfloat16*)alloc((size_t)M * 256 * 2);

    // xs = dinv-scaled bf16 x (M x 128), xa = aggregated (M x 128); both inside ybuf
    unsigned short* xs = (unsigned short*)ybuf;
    unsigned short* xa = (unsigned short*)ybuf + (size_t)M * 128;

    detect_ei<<<1, 64, 0, stream>>>((const unsigned int*)ei, flags);

    hipMemsetAsync(cnt, 0, (size_t)M * 4, stream);
    count_edges_dual<<<(E + 255) / 256, 256, 0, stream>>>(ei, cnt, E, M, flags);
    scan_blocks<<<NB, 256, 0, stream>>>(cnt, excl, bsum, M);
    scan_bsums<<<1, 256, 0, stream>>>(bsum, boff, NB, colptr, M);
    scan_add_dinv<<<NB, 256, 0, stream>>>(excl, boff, cnt, colptr, cursor, dinv, M);
    fill_csr_dual<<<(E + 255) / 256, 256, 0, stream>>>(ei, cursor, esrc, E, M, flags);
    transpose_all<<<(114688 + 255) / 256, 256, 0, stream>>>(W1, W2, W3, Wt1, Wt2, Wt3);

    int gmb = (M + 127) / 128;           // 391
    int ga  = (M + 3) / 4;               // 12500

    // Layer 1: aggregate first (S·x), then GEMM with fused bias+sigmoid
    prescale_x<<<((M * 128) + 255) / 256, 256, 0, stream>>>(x, dinv, xs, M * 128);
    aggregate_slice<128, false, false, false><<<dim3(ga, 2), 256, 0, stream>>>(
        xs, colptr, esrc, dinv, nullptr, xa, M, E);
    gemm_tile<128, 128, 256, false, 1><<<dim3(gmb, 2), 256, 0, stream>>>(
        xa, Wt1, dinv, b1, hbuf, M);
    // Layer 2
    gemm_tile<256, 128, 256, false, 0><<<dim3(gmb, 2), 256, 0, stream>>>(
        hbuf, Wt2, dinv, b2, ybuf, M);
    aggregate_slice<256, true, false, true><<<dim3(ga, 4), 256, 0, stream>>>(
        (const unsigned short*)ybuf, colptr, esrc, dinv, b2, hbuf, M, E);
    // Layer 3
    gemm_tile<256, 64, 64, false, 0><<<dim3(gmb, 1), 256, 0, stream>>>(
        hbuf, Wt3, dinv, b3, ybuf, M);
    aggregate_slice<64, false, true, true><<<dim3(ga, 1), 256, 0, stream>>>(
        (const unsigned short*)ybuf, colptr, esrc, dinv, b3, d_out, M, E);
}

// Round 8
// 396.703 us; speedup vs baseline: 1.1426x; 1.1426x over previous
//
#include <hip/hip_runtime.h>
#include <hip/hip_bf16.h>

typedef __bf16 bf16x8_t __attribute__((ext_vector_type(8)));
typedef float f32x4_t __attribute__((ext_vector_type(4)));

__device__ __forceinline__ float bits2f(unsigned int u) {
    union { unsigned int u; float f; } c; c.u = u; return c.f;
}
__device__ __forceinline__ unsigned short f2bf_bits(float f) {
    __hip_bfloat16 h = __float2bfloat16(f);
    return __builtin_bit_cast(unsigned short, h);
}

// ---------------- sentinel (ws too small) ----------------
__global__ void sentinel_fill(float* __restrict__ out, int n) {
    int i = blockIdx.x * blockDim.x + threadIdx.x;
    if (i < n) out[i] = 100.0f;
}

// ---------------- edge_index dtype detection (int64 vs int32) ----------------
__global__ void detect_ei(const unsigned int* __restrict__ ei, int* __restrict__ flags) {
    int lane = threadIdx.x;
    int cz = 0;
    #pragma unroll
    for (int j = 0; j < 4; ++j) {
        int idx = lane * 4 + j;          // 0..255
        cz += (ei[2 * idx + 1] == 0u);   // odd words zero => int64 storage
    }
    #pragma unroll
    for (int off = 32; off; off >>= 1) cz += __shfl_down(cz, off);
    if (lane == 0) flags[0] = (cz > 200);
}

// ---------------- CSR build ----------------

__global__ void count_edges_dual(const int* __restrict__ ei, int* __restrict__ cnt,
                                 int E, int M, const int* __restrict__ flags) {
    int e = blockIdx.x * blockDim.x + threadIdx.x;
    if (e < E) {
        int c = flags[0] ? ei[2 * E + 2 * e] : ei[E + e];
        if ((unsigned)c < (unsigned)M) atomicAdd(&cnt[c], 1);
    }
}

// phase 1: per-256-block exclusive scan + block sums
__global__ void scan_blocks(const int* __restrict__ cnt, int* __restrict__ excl,
                            int* __restrict__ bsum, int n) {
    int tid = threadIdx.x;
    int i = blockIdx.x * 256 + tid;
    int lane = tid & 63, wv = tid >> 6;
    __shared__ int ws[4];
    int v = (i < n) ? cnt[i] : 0;
    int s = v;
    #pragma unroll
    for (int off = 1; off < 64; off <<= 1) {
        int t = __shfl_up(s, off);
        if (lane >= off) s += t;
    }
    if (lane == 63) ws[wv] = s;
    __syncthreads();
    if (tid == 0) { int a = 0; for (int q = 0; q < 4; ++q) { int t = ws[q]; ws[q] = a; a += t; } }
    __syncthreads();
    int ex = s - v + ws[wv];
    if (i < n) excl[i] = ex;
    if (tid == 255) bsum[blockIdx.x] = ex + v;
}

// phase 2: single-block scan of block sums (+ writes colptr[n] total)
__global__ void scan_bsums(const int* __restrict__ bsum, int* __restrict__ boff,
                           int nb, int* __restrict__ colptr, int n) {
    int tid = threadIdx.x, lane = tid & 63, wv = tid >> 6;
    __shared__ int ws[4];
    __shared__ int carry;
    if (tid == 0) carry = 0;
    __syncthreads();
    for (int base = 0; base < nb; base += 256) {
        int i = base + tid;
        int v = (i < nb) ? bsum[i] : 0;
        int s = v;
        #pragma unroll
        for (int off = 1; off < 64; off <<= 1) {
            int t = __shfl_up(s, off);
            if (lane >= off) s += t;
        }
        if (lane == 63) ws[wv] = s;
        __syncthreads();
        if (tid == 0) { int a = carry; for (int q = 0; q < 4; ++q) { int t = ws[q]; ws[q] = a; a += t; } carry = a; }
        __syncthreads();
        int ex = s - v + ws[wv];
        if (i < nb) boff[i] = ex;
        __syncthreads();
    }
    if (tid == 0) colptr[n] = carry;
}

// phase 3: add block offsets; also compute dinv
__global__ void scan_add_dinv(const int* __restrict__ excl, const int* __restrict__ boff,
                              const int* __restrict__ cnt, int* __restrict__ colptr,
                              int* __restrict__ cursor, float* __restrict__ dinv, int n) {
    int i = blockIdx.x * 256 + threadIdx.x;
    if (i < n) {
        int v = excl[i] + boff[blockIdx.x];
        colptr[i] = v;
        cursor[i] = v;
        dinv[i] = rsqrtf((float)cnt[i] + 1.0f);
    }
}

__global__ void fill_csr_dual(const int* __restrict__ ei, int* __restrict__ cursor,
                              int* __restrict__ esrc, int E, int M,
                              const int* __restrict__ flags) {
    int e = blockIdx.x * blockDim.x + threadIdx.x;
    if (e < E) {
        int r, c;
        if (flags[0]) { r = ei[2 * e]; c = ei[2 * E + 2 * e]; }
        else          { r = ei[e];     c = ei[E + e]; }
        if ((unsigned)c < (unsigned)M && (unsigned)r < (unsigned)M) {
            int p = atomicAdd(&cursor[c], 1);
            if ((unsigned)p < (unsigned)E) esrc[p] = r;
        }
    }
}

// ---------------- fused weight transposes f32 -> bf16 (W^T layout) ----------------
__global__ void transpose_all(const float* __restrict__ W1, const float* __restrict__ W2,
                              const float* __restrict__ W3,
                              unsigned short* __restrict__ Wt1, unsigned short* __restrict__ Wt2,
                              unsigned short* __restrict__ Wt3) {
    int i = blockIdx.x * 256 + threadIdx.x;
    if (i < 32768) {                       // W1: 128x256
        int k = i >> 8, n = i & 255;
        Wt1[n * 128 + k] = f2bf_bits(W1[i]);
    } else if (i < 32768 + 65536) {        // W2: 256x256
        int j = i - 32768;
        int k = j >> 8, n = j & 255;
        Wt2[n * 256 + k] = f2bf_bits(W2[j]);
    } else if (i < 114688) {               // W3: 256x64
        int j = i - 98304;
        int k = j >> 6, n = j & 63;
        Wt3[n * 256 + k] = f2bf_bits(W3[j]);
    }
}

// ---------------- x pre-scale: xs[i][k] = bf16(x[i][k] * dinv[i]) ----------------
__global__ void prescale_x(const float* __restrict__ x, const float* __restrict__ dinv,
                           unsigned short* __restrict__ xs, int total) {
    int i = blockIdx.x * 256 + threadIdx.x;
    if (i < total) {
        int row = i >> 7;   // K=128
        xs[i] = f2bf_bits(x[i] * dinv[row]);
    }
}

// ---------------- tiled GEMM (bf16 MFMA) ----------------
// EPI=0: Y = dinv[m] * (A·B)   (bf16 out)
// EPI=1: Y = sigmoid(A·B + bias[n]) (bf16 out)
template<int K, int BN, int NTOT, bool AF32, int EPI>
__global__ __launch_bounds__(256) void gemm_tile(
    const void* __restrict__ A,
    const unsigned short* __restrict__ Bt,
    const float* __restrict__ dinv,
    const float* __restrict__ bias,
    __hip_bfloat16* __restrict__ Y,
    int M)
{
    constexpr int KP = K + 8;
    constexpr int NT = BN / 2 / 16;   // n-tiles per wave
    __shared__ unsigned short Bs[BN * KP];

    const int tid  = threadIdx.x;
    const int lane = tid & 63;
    const int wave = tid >> 6;        // 0..3
    const int wm   = wave >> 1;       // 0..1  row group
    const int wn   = wave & 1;        // 0..1  col group
    const int quad = lane >> 4;       // 0..3
    const int l16  = lane & 15;
    const int n0   = blockIdx.y * BN;

    constexpr int CH = BN * K / 8;    // 16B chunks
    for (int idx = tid; idx < CH; idx += 256) {
        int n  = idx / (K / 8);
        int k8 = idx - n * (K / 8);
        uint4 v = *(const uint4*)(Bt + (size_t)(n0 + n) * K + k8 * 8);
        *(uint4*)&Bs[n * KP + k8 * 8] = v;
    }
    __syncthreads();

    int mrow[4];
#pragma unroll
    for (int mt = 0; mt < 4; ++mt) {
        int r = blockIdx.x * 128 + wm * 64 + mt * 16 + l16;
        mrow[mt] = (r < M) ? r : (M - 1);
    }

    f32x4_t acc[4][NT];
#pragma unroll
    for (int mt = 0; mt < 4; ++mt)
#pragma unroll
        for (int t = 0; t < NT; ++t) acc[mt][t] = (f32x4_t){0.f, 0.f, 0.f, 0.f};

    const unsigned short* BsW = &Bs[(wn * (BN / 2)) * KP];

#pragma unroll
    for (int kc = 0; kc < K; kc += 32) {
        bf16x8_t a[4], b[NT];
#pragma unroll
        for (int mt = 0; mt < 4; ++mt) {
            if constexpr (AF32) {
                const float* Af = (const float*)A + (size_t)mrow[mt] * K + kc + quad * 8;
                float4 f0 = *(const float4*)(Af);
                float4 f1 = *(const float4*)(Af + 4);
                a[mt] = (bf16x8_t){(__bf16)f0.x, (__bf16)f0.y, (__bf16)f0.z, (__bf16)f0.w,
                                   (__bf16)f1.x, (__bf16)f1.y, (__bf16)f1.z, (__bf16)f1.w};
            } else {
                a[mt] = *(const bf16x8_t*)((const __bf16*)A + (size_t)mrow[mt] * K + kc + quad * 8);
            }
        }
#pragma unroll
        for (int t = 0; t < NT; ++t) {
            b[t] = *(const bf16x8_t*)&BsW[(t * 16 + l16) * KP + kc + quad * 8];
        }
#pragma unroll
        for (int mt = 0; mt < 4; ++mt)
#pragma unroll
            for (int t = 0; t < NT; ++t)
                acc[mt][t] = __builtin_amdgcn_mfma_f32_16x16x32_bf16(a[mt], b[t], acc[mt][t], 0, 0, 0);
    }

    float bv[NT];
    if constexpr (EPI == 1) {
#pragma unroll
        for (int t = 0; t < NT; ++t)
            bv[t] = bias[n0 + wn * (BN / 2) + t * 16 + l16];
    }

#pragma unroll
    for (int mt = 0; mt < 4; ++mt) {
        int rowbase = blockIdx.x * 128 + wm * 64 + mt * 16 + quad * 4;
#pragma unroll
        for (int r = 0; r < 4; ++r) {
            int rrow = rowbase + r;
            if (rrow < M) {
                if constexpr (EPI == 0) {
                    float dv = dinv[rrow];
#pragma unroll
                    for (int t = 0; t < NT; ++t) {
                        int ccol = n0 + wn * (BN / 2) + t * 16 + l16;
                        Y[(size_t)rrow * NTOT + ccol] = __float2bfloat16(acc[mt][t][r] * dv);
                    }
                } else {
#pragma unroll
                    for (int t = 0; t < NT; ++t) {
                        int ccol = n0 + wn * (BN / 2) + t * 16 + l16;
                        float o = acc[mt][t][r] + bv[t];
                        o = 1.f / (1.f + __expf(-o));
                        Y[(size_t)rrow * NTOT + ccol] = __float2bfloat16(o);
                    }
                }
            }
        }
    }
}

// ---------------- Monolithic aggregation, offset-shuffle inner loop ----------------
// out[i] = post(dinv[i]*(sum_{src} y[src] + y[i]) [+ bias]); one wave per node.
// G = C/8 lanes per row (16B each), EPW = 64/G edges in flight; 32-bit saddr offsets.
template<int C, bool SIG, bool OUTF32, bool HASB>
__global__ __launch_bounds__(256) void aggregate2(
    const unsigned short* __restrict__ Y,
    const int* __restrict__ colptr,
    const int* __restrict__ esrc,
    const float* __restrict__ dinv,
    const float* __restrict__ bias,
    void* __restrict__ H,
    int M, int Etot)
{
    constexpr int G   = C / 8;       // 256->32, 128->16, 64->8
    constexpr int EPW = 64 / G;      // 2, 4, 8
    const int lane = threadIdx.x & 63;
    const int wave = threadIdx.x >> 6;
    const int l = lane & (G - 1);
    const int g = lane / G;
    int node = blockIdx.x * 4 + wave;
    if (node >= M) return;

    int s = colptr[node];
    int e = colptr[node + 1];
    if (s < 0) s = 0;
    if (e > Etot) e = Etot;
    if (e < s) e = s;

    const char* Yb = (const char*)Y;
    const unsigned loff = (unsigned)(l * 16);   // byte offset within row

    float acc[8];
    #pragma unroll
    for (int k = 0; k < 8; ++k) acc[k] = 0.f;

    for (int base = s; base < e; base += 64) {
        int n = e - base; if (n > 64) n = 64;
        unsigned myOff = 0;
        if (lane < n) {
            unsigned src = (unsigned)esrc[base + lane];
            myOff = src * (unsigned)(C * 2);    // byte offset of row (shl)
        }
        int j = 0;
        #pragma unroll 2
        for (; j + EPW <= n; j += EPW) {
            unsigned off = __shfl(myOff, j + g) + loff;
            uint4 u = *(const uint4*)(Yb + off);
            acc[0] += bits2f(u.x << 16);
            acc[1] += bits2f(u.x & 0xffff0000u);
            acc[2] += bits2f(u.y << 16);
            acc[3] += bits2f(u.y & 0xffff0000u);
            acc[4] += bits2f(u.z << 16);
            acc[5] += bits2f(u.z & 0xffff0000u);
            acc[6] += bits2f(u.w << 16);
            acc[7] += bits2f(u.w & 0xffff0000u);
        }
        if (j < n) {           // tail: some groups idle
            unsigned off = __shfl(myOff, j + g) + loff;
            if (j + g < n) {
                uint4 u = *(const uint4*)(Yb + off);
                acc[0] += bits2f(u.x << 16);
                acc[1] += bits2f(u.x & 0xffff0000u);
                acc[2] += bits2f(u.y << 16);
                acc[3] += bits2f(u.y & 0xffff0000u);
                acc[4] += bits2f(u.z << 16);
                acc[5] += bits2f(u.z & 0xffff0000u);
                acc[6] += bits2f(u.w << 16);
                acc[7] += bits2f(u.w & 0xffff0000u);
            }
        }
    }
    // self-loop term (group 0 only, counted once)
    if (g == 0) {
        unsigned off = (unsigned)node * (unsigned)(C * 2) + loff;
        uint4 u = *(const uint4*)(Yb + off);
        acc[0] += bits2f(u.x << 16);
        acc[1] += bits2f(u.x & 0xffff0000u);
        acc[2] += bits2f(u.y << 16);
        acc[3] += bits2f(u.y & 0xffff0000u);
        acc[4] += bits2f(u.z << 16);
        acc[5] += bits2f(u.z & 0xffff0000u);
        acc[6] += bits2f(u.w << 16);
        acc[7] += bits2f(u.w & 0xffff0000u);
    }
    // cross-group reduction
    #pragma unroll
    for (int off = G; off < 64; off <<= 1) {
        #pragma unroll
        for (int k = 0; k < 8; ++k) acc[k] += __shfl_xor(acc[k], off);
    }

    if (g == 0) {   // lanes [0,G) hold channels [l*8, l*8+8)
        float dv = dinv[node];
        float o[8];
        #pragma unroll
        for (int k = 0; k < 8; ++k) {
            o[k] = acc[k] * dv;
            if (HASB) o[k] += bias[l * 8 + k];
            if (SIG) o[k] = 1.f / (1.f + __expf(-o[k]));
        }
        if constexpr (OUTF32) {
            float* Hp = (float*)H + (size_t)node * C + l * 8;
            *(float4*)Hp       = (float4){o[0], o[1], o[2], o[3]};
            *(float4*)(Hp + 4) = (float4){o[4], o[5], o[6], o[7]};
        } else {
            uint4 st;
            st.x = (unsigned int)f2bf_bits(o[0]) | ((unsigned int)f2bf_bits(o[1]) << 16);
            st.y = (unsigned int)f2bf_bits(o[2]) | ((unsigned int)f2bf_bits(o[3]) << 16);
            st.z = (unsigned int)f2bf_bits(o[4]) | ((unsigned int)f2bf_bits(o[5]) << 16);
            st.w = (unsigned int)f2bf_bits(o[6]) | ((unsigned int)f2bf_bits(o[7]) << 16);
            *(uint4*)((unsigned short*)H + (size_t)node * C + l * 8) = st;
        }
    }
}

// ---------------- launch ----------------

extern "C" void kernel_launch(void* const* d_in, const int* in_sizes, int n_in,
                              void* d_out, int out_size, void* d_ws, size_t ws_size,
                              hipStream_t stream)
{
    int iEI = 2, iW1 = 3, iB1 = 4, iW2 = 5, iB2 = 6, iW3 = 7, iB3 = 8;
    if (n_in == 8) { iEI = 1; iW1 = 2; iB1 = 3; iW2 = 4; iB2 = 5; iW3 = 6; iB3 = 7; }

    const float* x  = (const float*)d_in[0];
    const int* ei   = (const int*)d_in[iEI];
    const float* W1 = (const float*)d_in[iW1];
    const float* b1 = (const float*)d_in[iB1];
    const float* W2 = (const float*)d_in[iW2];
    const float* b2 = (const float*)d_in[iB2];
    const float* W3 = (const float*)d_in[iW3];
    const float* b3 = (const float*)d_in[iB3];

    const int M = in_sizes[0] / 128;     // 50000
    const int E = in_sizes[iEI] / 2;     // 800000
    const int NB = (M + 255) / 256;      // scan blocks

    auto rnd = [](size_t b) { return (b + 255) & ~(size_t)255; };
    size_t needed = rnd(64 * 4)                          // flags
                  + rnd((size_t)M * 4) * 2               // dinv, cnt
                  + rnd((size_t)(M + 1) * 4)             // colptr
                  + rnd((size_t)M * 4)                   // cursor
                  + rnd((size_t)M * 4)                   // excl
                  + rnd((size_t)(NB + 1) * 4) * 2        // bsum, boff
                  + rnd((size_t)E * 4)                   // esrc
                  + rnd((size_t)256 * 128 * 2)           // Wt1
                  + rnd((size_t)256 * 256 * 2)           // Wt2
                  + rnd((size_t)64 * 256 * 2)            // Wt3
                  + rnd((size_t)M * 256 * 2) * 2;        // ybuf, hbuf
    if (ws_size < needed) {
        sentinel_fill<<<(out_size + 255) / 256, 256, 0, stream>>>((float*)d_out, out_size);
        return;
    }

    char* p = (char*)d_ws;
    auto alloc = [&](size_t bytes) {
        char* r = p;
        p += (bytes + 255) & ~(size_t)255;
        return r;
    };
    int* flags  = (int*)alloc(64 * 4);
    float* dinv = (float*)alloc((size_t)M * 4);
    int* cnt    = (int*)alloc((size_t)M * 4);
    int* colptr = (int*)alloc((size_t)(M + 1) * 4);
    int* cursor = (int*)alloc((size_t)M * 4);
    int* excl   = (int*)alloc((size_t)M * 4);
    int* bsum   = (int*)alloc((size_t)(NB + 1) * 4);
    int* boff   = (int*)alloc((size_t)(NB + 1) * 4);
    int* esrc   = (int*)alloc((size_t)E * 4);
    unsigned short* Wt1 = (unsigned short*)alloc((size_t)256 * 128 * 2);
    unsigned short* Wt2 = (unsigned short*)alloc((size_t)256 * 256 * 2);
    unsigned short* Wt3 = (unsigned short*)alloc((size_t)64 * 256 * 2);
    __hip_bfloat16* ybuf = (__hip_bfloat16*)alloc((size_t)M * 256 * 2);
    __hip_bfloat16* hbuf = (__hip_bfloat16*)alloc((size_t)M * 256 * 2);

    // xs = dinv-scaled bf16 x (M x 128), xa = aggregated (M x 128); both inside ybuf
    unsigned short* xs = (unsigned short*)ybuf;
    unsigned short* xa = (unsigned short*)ybuf + (size_t)M * 128;

    detect_ei<<<1, 64, 0, stream>>>((const unsigned int*)ei, flags);

    hipMemsetAsync(cnt, 0, (size_t)M * 4, stream);
    count_edges_dual<<<(E + 255) / 256, 256, 0, stream>>>(ei, cnt, E, M, flags);
    scan_blocks<<<NB, 256, 0, stream>>>(cnt, excl, bsum, M);
    scan_bsums<<<1, 256, 0, stream>>>(bsum, boff, NB, colptr, M);
    scan_add_dinv<<<NB, 256, 0, stream>>>(excl, boff, cnt, colptr, cursor, dinv, M);
    fill_csr_dual<<<(E + 255) / 256, 256, 0, stream>>>(ei, cursor, esrc, E, M, flags);
    transpose_all<<<(114688 + 255) / 256, 256, 0, stream>>>(W1, W2, W3, Wt1, Wt2, Wt3);

    int gmb = (M + 127) / 128;           // 391
    int ga  = (M + 3) / 4;               // 12500

    // Layer 1: aggregate x first (S·x), then GEMM with fused bias+sigmoid
    prescale_x<<<((M * 128) + 255) / 256, 256, 0, stream>>>(x, dinv, xs, M * 128);
    aggregate2<128, false, false, false><<<ga, 256, 0, stream>>>(
        xs, colptr, esrc, dinv, nullptr, xa, M, E);
    gemm_tile<128, 128, 256, false, 1><<<dim3(gmb, 2), 256, 0, stream>>>(
        xa, Wt1, dinv, b1, hbuf, M);
    // Layer 2
    gemm_tile<256, 128, 256, false, 0><<<dim3(gmb, 2), 256, 0, stream>>>(
        hbuf, Wt2, dinv, b2, ybuf, M);
    aggregate2<256, true, false, true><<<ga, 256, 0, stream>>>(
        (const unsigned short*)ybuf, colptr, esrc, dinv, b2, hbuf, M, E);
    // Layer 3
    gemm_tile<256, 64, 64, false, 0><<<dim3(gmb, 1), 256, 0, stream>>>(
        hbuf, Wt3, dinv, b3, ybuf, M);
    aggregate2<64, false, true, true><<<ga, 256, 0, stream>>>(
        (const unsigned short*)ybuf, colptr, esrc, dinv, b3, d_out, M, E);
}

// Round 9
// 382.437 us; speedup vs baseline: 1.1852x; 1.0373x over previous
//
#include <hip/hip_runtime.h>
#include <hip/hip_bf16.h>

typedef __bf16 bf16x8_t __attribute__((ext_vector_type(8)));
typedef float f32x4_t __attribute__((ext_vector_type(4)));

__device__ __forceinline__ float bits2f(unsigned int u) {
    union { unsigned int u; float f; } c; c.u = u; return c.f;
}
__device__ __forceinline__ unsigned short f2bf_bits(float f) {
    __hip_bfloat16 h = __float2bfloat16(f);
    return __builtin_bit_cast(unsigned short, h);
}

// ---------------- sentinel (ws too small) ----------------
__global__ void sentinel_fill(float* __restrict__ out, int n) {
    int i = blockIdx.x * blockDim.x + threadIdx.x;
    if (i < n) out[i] = 100.0f;
}

// ---------------- edge_index dtype detection (int64 vs int32) ----------------
__global__ void detect_ei(const unsigned int* __restrict__ ei, int* __restrict__ flags) {
    int lane = threadIdx.x;
    int cz = 0;
    #pragma unroll
    for (int j = 0; j < 4; ++j) {
        int idx = lane * 4 + j;          // 0..255
        cz += (ei[2 * idx + 1] == 0u);   // odd words zero => int64 storage
    }
    #pragma unroll
    for (int off = 32; off; off >>= 1) cz += __shfl_down(cz, off);
    if (lane == 0) flags[0] = (cz > 200);
}

// ---------------- CSR build ----------------

__global__ void count_edges_dual(const int* __restrict__ ei, int* __restrict__ cnt,
                                 int E, int M, const int* __restrict__ flags) {
    int e = blockIdx.x * blockDim.x + threadIdx.x;
    if (e < E) {
        int c = flags[0] ? ei[2 * E + 2 * e] : ei[E + e];
        if ((unsigned)c < (unsigned)M) atomicAdd(&cnt[c], 1);
    }
}

// phase 1: per-256-block exclusive scan + block sums
__global__ void scan_blocks(const int* __restrict__ cnt, int* __restrict__ excl,
                            int* __restrict__ bsum, int n) {
    int tid = threadIdx.x;
    int i = blockIdx.x * 256 + tid;
    int lane = tid & 63, wv = tid >> 6;
    __shared__ int ws[4];
    int v = (i < n) ? cnt[i] : 0;
    int s = v;
    #pragma unroll
    for (int off = 1; off < 64; off <<= 1) {
        int t = __shfl_up(s, off);
        if (lane >= off) s += t;
    }
    if (lane == 63) ws[wv] = s;
    __syncthreads();
    if (tid == 0) { int a = 0; for (int q = 0; q < 4; ++q) { int t = ws[q]; ws[q] = a; a += t; } }
    __syncthreads();
    int ex = s - v + ws[wv];
    if (i < n) excl[i] = ex;
    if (tid == 255) bsum[blockIdx.x] = ex + v;
}

// phase 2: single-block scan of block sums (+ writes colptr[n] total)
__global__ void scan_bsums(const int* __restrict__ bsum, int* __restrict__ boff,
                           int nb, int* __restrict__ colptr, int n) {
    int tid = threadIdx.x, lane = tid & 63, wv = tid >> 6;
    __shared__ int ws[4];
    __shared__ int carry;
    if (tid == 0) carry = 0;
    __syncthreads();
    for (int base = 0; base < nb; base += 256) {
        int i = base + tid;
        int v = (i < nb) ? bsum[i] : 0;
        int s = v;
        #pragma unroll
        for (int off = 1; off < 64; off <<= 1) {
            int t = __shfl_up(s, off);
            if (lane >= off) s += t;
        }
        if (lane == 63) ws[wv] = s;
        __syncthreads();
        if (tid == 0) { int a = carry; for (int q = 0; q < 4; ++q) { int t = ws[q]; ws[q] = a; a += t; } carry = a; }
        __syncthreads();
        int ex = s - v + ws[wv];
        if (i < nb) boff[i] = ex;
        __syncthreads();
    }
    if (tid == 0) colptr[n] = carry;
}

// phase 3: add block offsets; also compute dinv
__global__ void scan_add_dinv(const int* __restrict__ excl, const int* __restrict__ boff,
                              const int* __restrict__ cnt, int* __restrict__ colptr,
                              int* __restrict__ cursor, float* __restrict__ dinv, int n) {
    int i = blockIdx.x * 256 + threadIdx.x;
    if (i < n) {
        int v = excl[i] + boff[blockIdx.x];
        colptr[i] = v;
        cursor[i] = v;
        dinv[i] = rsqrtf((float)cnt[i] + 1.0f);
    }
}

__global__ void fill_csr_dual(const int* __restrict__ ei, int* __restrict__ cursor,
                              int* __restrict__ esrc, int E, int M,
                              const int* __restrict__ flags) {
    int e = blockIdx.x * blockDim.x + threadIdx.x;
    if (e < E) {
        int r, c;
        if (flags[0]) { r = ei[2 * e]; c = ei[2 * E + 2 * e]; }
        else          { r = ei[e];     c = ei[E + e]; }
        if ((unsigned)c < (unsigned)M && (unsigned)r < (unsigned)M) {
            int p = atomicAdd(&cursor[c], 1);
            if ((unsigned)p < (unsigned)E) esrc[p] = r;
        }
    }
}

// ---------------- fused weight transposes f32 -> bf16 (W^T layout) ----------------
__global__ void transpose_all(const float* __restrict__ W1, const float* __restrict__ W2,
                              const float* __restrict__ W3,
                              unsigned short* __restrict__ Wt1, unsigned short* __restrict__ Wt2,
                              unsigned short* __restrict__ Wt3) {
    int i = blockIdx.x * 256 + threadIdx.x;
    if (i < 32768) {                       // W1: 128x256
        int k = i >> 8, n = i & 255;
        Wt1[n * 128 + k] = f2bf_bits(W1[i]);
    } else if (i < 32768 + 65536) {        // W2: 256x256
        int j = i - 32768;
        int k = j >> 8, n = j & 255;
        Wt2[n * 256 + k] = f2bf_bits(W2[j]);
    } else if (i < 114688) {               // W3: 256x64
        int j = i - 98304;
        int k = j >> 6, n = j & 63;
        Wt3[n * 256 + k] = f2bf_bits(W3[j]);
    }
}

// ---------------- x pre-scale: xs[i][k] = bf16(x[i][k] * dinv[i]) ----------------
__global__ void prescale_x(const float* __restrict__ x, const float* __restrict__ dinv,
                           unsigned short* __restrict__ xs, int total) {
    int i = blockIdx.x * 256 + threadIdx.x;
    if (i < total) {
        int row = i >> 7;   // K=128
        xs[i] = f2bf_bits(x[i] * dinv[row]);
    }
}

// ---------------- tiled GEMM (bf16 MFMA), K-split staging ----------------
// EPI=0: Y(bf16) = dinv[m] * (A·B)
// EPI=1: Y(bf16) = sigmoid(A·B + bias[n])
// EPI=2: Y(fp8 e4m3) = dinv[m] * (A·B)
template<int K, int BN, int NTOT, int EPI>
__global__ __launch_bounds__(256) void gemm_tile(
    const __bf16* __restrict__ A,
    const unsigned short* __restrict__ Bt,
    const float* __restrict__ dinv,
    const float* __restrict__ bias,
    void* __restrict__ Y,
    int M)
{
    constexpr int KS = (K > 128) ? 128 : K;   // staged chunk
    constexpr int KP = KS + 8;
    constexpr int NT = BN / 2 / 16;   // n-tiles per wave
    __shared__ unsigned short Bs[BN * KP];

    const int tid  = threadIdx.x;
    const int lane = tid & 63;
    const int wave = tid >> 6;        // 0..3
    const int wm   = wave >> 1;       // 0..1  row group
    const int wn   = wave & 1;        // 0..1  col group
    const int quad = lane >> 4;       // 0..3
    const int l16  = lane & 15;
    const int n0   = blockIdx.y * BN;

    int mrow[4];
#pragma unroll
    for (int mt = 0; mt < 4; ++mt) {
        int r = blockIdx.x * 128 + wm * 64 + mt * 16 + l16;
        mrow[mt] = (r < M) ? r : (M - 1);
    }

    f32x4_t acc[4][NT];
#pragma unroll
    for (int mt = 0; mt < 4; ++mt)
#pragma unroll
        for (int t = 0; t < NT; ++t) acc[mt][t] = (f32x4_t){0.f, 0.f, 0.f, 0.f};

    const unsigned short* BsW = &Bs[(wn * (BN / 2)) * KP];

    for (int kh = 0; kh < K; kh += KS) {
        // stage B chunk
        constexpr int CH = BN * KS / 8;    // 16B chunks
        for (int idx = tid; idx < CH; idx += 256) {
            int n  = idx / (KS / 8);
            int k8 = idx - n * (KS / 8);
            uint4 v = *(const uint4*)(Bt + (size_t)(n0 + n) * K + kh + k8 * 8);
            *(uint4*)&Bs[n * KP + k8 * 8] = v;
        }
        __syncthreads();

#pragma unroll
        for (int kc = 0; kc < KS; kc += 32) {
            bf16x8_t a[4], b[NT];
#pragma unroll
            for (int mt = 0; mt < 4; ++mt)
                a[mt] = *(const bf16x8_t*)(A + (size_t)mrow[mt] * K + kh + kc + quad * 8);
#pragma unroll
            for (int t = 0; t < NT; ++t)
                b[t] = *(const bf16x8_t*)&BsW[(t * 16 + l16) * KP + kc + quad * 8];
#pragma unroll
            for (int mt = 0; mt < 4; ++mt)
#pragma unroll
                for (int t = 0; t < NT; ++t)
                    acc[mt][t] = __builtin_amdgcn_mfma_f32_16x16x32_bf16(a[mt], b[t], acc[mt][t], 0, 0, 0);
        }
        if (kh + KS < K) __syncthreads();
    }

    float bv[NT];
    if constexpr (EPI == 1) {
#pragma unroll
        for (int t = 0; t < NT; ++t)
            bv[t] = bias[n0 + wn * (BN / 2) + t * 16 + l16];
    }

#pragma unroll
    for (int mt = 0; mt < 4; ++mt) {
        int rowbase = blockIdx.x * 128 + wm * 64 + mt * 16 + quad * 4;
#pragma unroll
        for (int r = 0; r < 4; ++r) {
            int rrow = rowbase + r;
            if (rrow < M) {
                if constexpr (EPI == 0) {
                    float dv = dinv[rrow];
#pragma unroll
                    for (int t = 0; t < NT; ++t) {
                        int ccol = n0 + wn * (BN / 2) + t * 16 + l16;
                        ((__hip_bfloat16*)Y)[(size_t)rrow * NTOT + ccol] =
                            __float2bfloat16(acc[mt][t][r] * dv);
                    }
                } else if constexpr (EPI == 1) {
#pragma unroll
                    for (int t = 0; t < NT; ++t) {
                        int ccol = n0 + wn * (BN / 2) + t * 16 + l16;
                        float o = acc[mt][t][r] + bv[t];
                        o = 1.f / (1.f + __expf(-o));
                        ((__hip_bfloat16*)Y)[(size_t)rrow * NTOT + ccol] = __float2bfloat16(o);
                    }
                } else {
                    float dv = dinv[rrow];
#pragma unroll
                    for (int t = 0; t < NT; ++t) {
                        int ccol = n0 + wn * (BN / 2) + t * 16 + l16;
                        float o = acc[mt][t][r] * dv;
                        int pk = __builtin_amdgcn_cvt_pk_fp8_f32(o, o, 0, false);
                        ((unsigned char*)Y)[(size_t)rrow * NTOT + ccol] = (unsigned char)(pk & 0xff);
                    }
                }
            }
        }
    }
}

// ---------------- fp8 aggregation for C=256 (layer 2) ----------------
// out(bf16)[i] = sigmoid(dinv[i]*(sum y8[src] + y8[i]) + bias); one wave per node.
// 16 lanes x 16B per 256B fp8 row, 4 edges in flight.
__global__ __launch_bounds__(256) void aggregate_fp8_256(
    const unsigned char* __restrict__ Y8,
    const int* __restrict__ colptr,
    const int* __restrict__ esrc,
    const float* __restrict__ dinv,
    const float* __restrict__ bias,
    unsigned short* __restrict__ H,
    int M, int Etot)
{
    const int lane = threadIdx.x & 63;
    const int wave = threadIdx.x >> 6;
    const int l = lane & 15;       // 16B sub-offset
    const int g = lane >> 4;       // 0..3 edge group
    int node = blockIdx.x * 4 + wave;
    if (node >= M) return;

    int s = colptr[node];
    int e = colptr[node + 1];
    if (s < 0) s = 0;
    if (e > Etot) e = Etot;
    if (e < s) e = s;

    const char* Yb = (const char*)Y8;
    const unsigned loff = (unsigned)(l * 16);

    float acc[16];
    #pragma unroll
    for (int k = 0; k < 16; ++k) acc[k] = 0.f;

    auto unpack = [&](uint4 u) {
        auto p0 = __builtin_amdgcn_cvt_pk_f32_fp8(u.x, false);
        auto p1 = __builtin_amdgcn_cvt_pk_f32_fp8(u.x, true);
        auto p2 = __builtin_amdgcn_cvt_pk_f32_fp8(u.y, false);
        auto p3 = __builtin_amdgcn_cvt_pk_f32_fp8(u.y, true);
        auto p4 = __builtin_amdgcn_cvt_pk_f32_fp8(u.z, false);
        auto p5 = __builtin_amdgcn_cvt_pk_f32_fp8(u.z, true);
        auto p6 = __builtin_amdgcn_cvt_pk_f32_fp8(u.w, false);
        auto p7 = __builtin_amdgcn_cvt_pk_f32_fp8(u.w, true);
        acc[0]  += p0[0]; acc[1]  += p0[1];
        acc[2]  += p1[0]; acc[3]  += p1[1];
        acc[4]  += p2[0]; acc[5]  += p2[1];
        acc[6]  += p3[0]; acc[7]  += p3[1];
        acc[8]  += p4[0]; acc[9]  += p4[1];
        acc[10] += p5[0]; acc[11] += p5[1];
        acc[12] += p6[0]; acc[13] += p6[1];
        acc[14] += p7[0]; acc[15] += p7[1];
    };

    for (int base = s; base < e; base += 64) {
        int n = e - base; if (n > 64) n = 64;
        unsigned myOff = 0;
        if (lane < n) myOff = (unsigned)esrc[base + lane] << 8;   // 256B rows
        int j = 0;
        #pragma unroll 2
        for (; j + 4 <= n; j += 4) {
            unsigned off = __shfl(myOff, j + g) + loff;
            uint4 u = *(const uint4*)(Yb + off);
            unpack(u);
        }
        if (j < n) {
            unsigned off = __shfl(myOff, j + g) + loff;
            if (j + g < n) {
                uint4 u = *(const uint4*)(Yb + off);
                unpack(u);
            }
        }
    }
    // self-loop (group 0 only)
    if (g == 0) {
        uint4 u = *(const uint4*)(Yb + ((unsigned)node << 8) + loff);
        unpack(u);
    }
    // cross-group reduction (4 groups of 16)
    #pragma unroll
    for (int off = 16; off < 64; off <<= 1) {
        #pragma unroll
        for (int k = 0; k < 16; ++k) acc[k] += __shfl_xor(acc[k], off);
    }

    if (g == 0) {   // lanes 0..15 hold channels [l*16, l*16+16)
        float dv = dinv[node];
        float o[16];
        #pragma unroll
        for (int k = 0; k < 16; ++k) {
            o[k] = acc[k] * dv + bias[l * 16 + k];
            o[k] = 1.f / (1.f + __expf(-o[k]));
        }
        uint4 s0, s1;
        s0.x = (unsigned)f2bf_bits(o[0])  | ((unsigned)f2bf_bits(o[1])  << 16);
        s0.y = (unsigned)f2bf_bits(o[2])  | ((unsigned)f2bf_bits(o[3])  << 16);
        s0.z = (unsigned)f2bf_bits(o[4])  | ((unsigned)f2bf_bits(o[5])  << 16);
        s0.w = (unsigned)f2bf_bits(o[6])  | ((unsigned)f2bf_bits(o[7])  << 16);
        s1.x = (unsigned)f2bf_bits(o[8])  | ((unsigned)f2bf_bits(o[9])  << 16);
        s1.y = (unsigned)f2bf_bits(o[10]) | ((unsigned)f2bf_bits(o[11]) << 16);
        s1.z = (unsigned)f2bf_bits(o[12]) | ((unsigned)f2bf_bits(o[13]) << 16);
        s1.w = (unsigned)f2bf_bits(o[14]) | ((unsigned)f2bf_bits(o[15]) << 16);
        unsigned short* Hp = H + (size_t)node * 256 + l * 16;
        *(uint4*)Hp       = s0;
        *(uint4*)(Hp + 8) = s1;
    }
}

// ---------------- bf16 monolithic aggregation (layers 1 & 3) ----------------
template<int C, bool SIG, bool OUTF32, bool HASB>
__global__ __launch_bounds__(256) void aggregate2(
    const unsigned short* __restrict__ Y,
    const int* __restrict__ colptr,
    const int* __restrict__ esrc,
    const float* __restrict__ dinv,
    const float* __restrict__ bias,
    void* __restrict__ H,
    int M, int Etot)
{
    constexpr int G   = C / 8;       // 128->16, 64->8
    constexpr int EPW = 64 / G;      // 4, 8
    const int lane = threadIdx.x & 63;
    const int wave = threadIdx.x >> 6;
    const int l = lane & (G - 1);
    const int g = lane / G;
    int node = blockIdx.x * 4 + wave;
    if (node >= M) return;

    int s = colptr[node];
    int e = colptr[node + 1];
    if (s < 0) s = 0;
    if (e > Etot) e = Etot;
    if (e < s) e = s;

    const char* Yb = (const char*)Y;
    const unsigned loff = (unsigned)(l * 16);

    float acc[8];
    #pragma unroll
    for (int k = 0; k < 8; ++k) acc[k] = 0.f;

    auto unpack = [&](uint4 u) {
        acc[0] += bits2f(u.x << 16);
        acc[1] += bits2f(u.x & 0xffff0000u);
        acc[2] += bits2f(u.y << 16);
        acc[3] += bits2f(u.y & 0xffff0000u);
        acc[4] += bits2f(u.z << 16);
        acc[5] += bits2f(u.z & 0xffff0000u);
        acc[6] += bits2f(u.w << 16);
        acc[7] += bits2f(u.w & 0xffff0000u);
    };

    for (int base = s; base < e; base += 64) {
        int n = e - base; if (n > 64) n = 64;
        unsigned myOff = 0;
        if (lane < n) myOff = (unsigned)esrc[base + lane] * (unsigned)(C * 2);
        int j = 0;
        #pragma unroll 2
        for (; j + EPW <= n; j += EPW) {
            unsigned off = __shfl(myOff, j + g) + loff;
            uint4 u = *(const uint4*)(Yb + off);
            unpack(u);
        }
        if (j < n) {
            unsigned off = __shfl(myOff, j + g) + loff;
            if (j + g < n) {
                uint4 u = *(const uint4*)(Yb + off);
                unpack(u);
            }
        }
    }
    if (g == 0) {
        unsigned off = (unsigned)node * (unsigned)(C * 2) + loff;
        uint4 u = *(const uint4*)(Yb + off);
        unpack(u);
    }
    #pragma unroll
    for (int off = G; off < 64; off <<= 1) {
        #pragma unroll
        for (int k = 0; k < 8; ++k) acc[k] += __shfl_xor(acc[k], off);
    }

    if (g == 0) {
        float dv = dinv[node];
        float o[8];
        #pragma unroll
        for (int k = 0; k < 8; ++k) {
            o[k] = acc[k] * dv;
            if (HASB) o[k] += bias[l * 8 + k];
            if (SIG) o[k] = 1.f / (1.f + __expf(-o[k]));
        }
        if constexpr (OUTF32) {
            float* Hp = (float*)H + (size_t)node * C + l * 8;
            *(float4*)Hp       = (float4){o[0], o[1], o[2], o[3]};
            *(float4*)(Hp + 4) = (float4){o[4], o[5], o[6], o[7]};
        } else {
            uint4 st;
            st.x = (unsigned)f2bf_bits(o[0]) | ((unsigned)f2bf_bits(o[1]) << 16);
            st.y = (unsigned)f2bf_bits(o[2]) | ((unsigned)f2bf_bits(o[3]) << 16);
            st.z = (unsigned)f2bf_bits(o[4]) | ((unsigned)f2bf_bits(o[5]) << 16);
            st.w = (unsigned)f2bf_bits(o[6]) | ((unsigned)f2bf_bits(o[7]) << 16);
            *(uint4*)((unsigned short*)H + (size_t)node * C + l * 8) = st;
        }
    }
}

// ---------------- launch ----------------

extern "C" void kernel_launch(void* const* d_in, const int* in_sizes, int n_in,
                              void* d_out, int out_size, void* d_ws, size_t ws_size,
                              hipStream_t stream)
{
    int iEI = 2, iW1 = 3, iB1 = 4, iW2 = 5, iB2 = 6, iW3 = 7, iB3 = 8;
    if (n_in == 8) { iEI = 1; iW1 = 2; iB1 = 3; iW2 = 4; iB2 = 5; iW3 = 6; iB3 = 7; }

    const float* x  = (const float*)d_in[0];
    const int* ei   = (const int*)d_in[iEI];
    const float* W1 = (const float*)d_in[iW1];
    const float* b1 = (const float*)d_in[iB1];
    const float* W2 = (const float*)d_in[iW2];
    const float* b2 = (const float*)d_in[iB2];
    const float* W3 = (const float*)d_in[iW3];
    const float* b3 = (const float*)d_in[iB3];

    const int M = in_sizes[0] / 128;     // 50000
    const int E = in_sizes[iEI] / 2;     // 800000
    const int NB = (M + 255) / 256;      // scan blocks

    auto rnd = [](size_t b) { return (b + 255) & ~(size_t)255; };
    size_t needed = rnd(64 * 4)                          // flags
                  + rnd((size_t)M * 4) * 2               // dinv, cnt
                  + rnd((size_t)(M + 1) * 4)             // colptr
                  + rnd((size_t)M * 4)                   // cursor
                  + rnd((size_t)M * 4)                   // excl
                  + rnd((size_t)(NB + 1) * 4) * 2        // bsum, boff
                  + rnd((size_t)E * 4)                   // esrc
                  + rnd((size_t)256 * 128 * 2)           // Wt1
                  + rnd((size_t)256 * 256 * 2)           // Wt2
                  + rnd((size_t)64 * 256 * 2)            // Wt3
                  + rnd((size_t)M * 256 * 2) * 2;        // ybuf, hbuf
    if (ws_size < needed) {
        sentinel_fill<<<(out_size + 255) / 256, 256, 0, stream>>>((float*)d_out, out_size);
        return;
    }

    char* p = (char*)d_ws;
    auto alloc = [&](size_t bytes) {
        char* r = p;
        p += (bytes + 255) & ~(size_t)255;
        return r;
    };
    int* flags  = (int*)alloc(64 * 4);
    float* dinv = (float*)alloc((size_t)M * 4);
    int* cnt    = (int*)alloc((size_t)M * 4);
    int* colptr = (int*)alloc((size_t)(M + 1) * 4);
    int* cursor = (int*)alloc((size_t)M * 4);
    int* excl   = (int*)alloc((size_t)M * 4);
    int* bsum   = (int*)alloc((size_t)(NB + 1) * 4);
    int* boff   = (int*)alloc((size_t)(NB + 1) * 4);
    int* esrc   = (int*)alloc((size_t)E * 4);
    unsigned short* Wt1 = (unsigned short*)alloc((size_t)256 * 128 * 2);
    unsigned short* Wt2 = (unsigned short*)alloc((size_t)256 * 256 * 2);
    unsigned short* Wt3 = (unsigned short*)alloc((size_t)64 * 256 * 2);
    __hip_bfloat16* ybuf = (__hip_bfloat16*)alloc((size_t)M * 256 * 2);
    __hip_bfloat16* hbuf = (__hip_bfloat16*)alloc((size_t)M * 256 * 2);

    // region reuse inside ybuf:
    unsigned short* xs = (unsigned short*)ybuf;                    // M x 128 bf16
    unsigned short* xa = (unsigned short*)ybuf + (size_t)M * 128;  // M x 128 bf16
    unsigned char*  y8 = (unsigned char*)ybuf;                     // M x 256 fp8 (after xs dead)

    detect_ei<<<1, 64, 0, stream>>>((const unsigned int*)ei, flags);

    hipMemsetAsync(cnt, 0, (size_t)M * 4, stream);
    count_edges_dual<<<(E + 255) / 256, 256, 0, stream>>>(ei, cnt, E, M, flags);
    scan_blocks<<<NB, 256, 0, stream>>>(cnt, excl, bsum, M);
    scan_bsums<<<1, 256, 0, stream>>>(bsum, boff, NB, colptr, M);
    scan_add_dinv<<<NB, 256, 0, stream>>>(excl, boff, cnt, colptr, cursor, dinv, M);
    fill_csr_dual<<<(E + 255) / 256, 256, 0, stream>>>(ei, cursor, esrc, E, M, flags);
    transpose_all<<<(114688 + 255) / 256, 256, 0, stream>>>(W1, W2, W3, Wt1, Wt2, Wt3);

    int gmb = (M + 127) / 128;           // 391
    int ga  = (M + 3) / 4;               // 12500

    // Layer 1: aggregate x first (S·x), then GEMM with fused bias+sigmoid
    prescale_x<<<((M * 128) + 255) / 256, 256, 0, stream>>>(x, dinv, xs, M * 128);
    aggregate2<128, false, false, false><<<ga, 256, 0, stream>>>(
        xs, colptr, esrc, dinv, nullptr, xa, M, E);
    gemm_tile<128, 128, 256, 1><<<dim3(gmb, 2), 256, 0, stream>>>(
        (const __bf16*)xa, Wt1, dinv, b1, hbuf, M);
    // Layer 2: GEMM -> fp8 table, fp8 gather aggregate -> bf16 h2
    gemm_tile<256, 128, 256, 2><<<dim3(gmb, 2), 256, 0, stream>>>(
        (const __bf16*)hbuf, Wt2, dinv, b2, y8, M);
    aggregate_fp8_256<<<ga, 256, 0, stream>>>(
        y8, colptr, esrc, dinv, b2, (unsigned short*)hbuf, M, E);
    // Layer 3: bf16
    gemm_tile<256, 64, 64, 0><<<dim3(gmb, 1), 256, 0, stream>>>(
        (const __bf16*)hbuf, Wt3, dinv, b3, ybuf, M);
    aggregate2<64, false, true, true><<<ga, 256, 0, stream>>>(
        (const unsigned short*)ybuf, colptr, esrc, dinv, b3, d_out, M, E);
}

// Round 10
// 346.165 us; speedup vs baseline: 1.3094x; 1.1048x over previous
//
#include <hip/hip_runtime.h>
#include <hip/hip_bf16.h>

typedef __bf16 bf16x8_t __attribute__((ext_vector_type(8)));
typedef float f32x4_t __attribute__((ext_vector_type(4)));

__device__ __forceinline__ float bits2f(unsigned int u) {
    union { unsigned int u; float f; } c; c.u = u; return c.f;
}
__device__ __forceinline__ unsigned short f2bf_bits(float f) {
    __hip_bfloat16 h = __float2bfloat16(f);
    return __builtin_bit_cast(unsigned short, h);
}

// ---------------- sentinel (ws too small) ----------------
__global__ void sentinel_fill(float* __restrict__ out, int n) {
    int i = blockIdx.x * blockDim.x + threadIdx.x;
    if (i < n) out[i] = 100.0f;
}

// ---------------- edge_index dtype detection (int64 vs int32) ----------------
__global__ void detect_ei(const unsigned int* __restrict__ ei, int* __restrict__ flags) {
    int lane = threadIdx.x;
    int cz = 0;
    #pragma unroll
    for (int j = 0; j < 4; ++j) {
        int idx = lane * 4 + j;          // 0..255
        cz += (ei[2 * idx + 1] == 0u);   // odd words zero => int64 storage
    }
    #pragma unroll
    for (int off = 32; off; off >>= 1) cz += __shfl_down(cz, off);
    if (lane == 0) flags[0] = (cz > 200);
}

// ---------------- CSR build ----------------

// count + per-edge rank (atomic return). rank write is coalesced.
__global__ void count_rank_dual(const int* __restrict__ ei, int* __restrict__ cnt,
                                int* __restrict__ rank, int E, int M,
                                const int* __restrict__ flags) {
    int e = blockIdx.x * blockDim.x + threadIdx.x;
    if (e < E) {
        int c = flags[0] ? ei[2 * E + 2 * e] : ei[E + e];
        int rk = 0;
        if ((unsigned)c < (unsigned)M) rk = atomicAdd(&cnt[c], 1);
        rank[e] = rk;
    }
}

// phase 1: per-256-block exclusive scan + block sums
__global__ void scan_blocks(const int* __restrict__ cnt, int* __restrict__ excl,
                            int* __restrict__ bsum, int n) {
    int tid = threadIdx.x;
    int i = blockIdx.x * 256 + tid;
    int lane = tid & 63, wv = tid >> 6;
    __shared__ int ws[4];
    int v = (i < n) ? cnt[i] : 0;
    int s = v;
    #pragma unroll
    for (int off = 1; off < 64; off <<= 1) {
        int t = __shfl_up(s, off);
        if (lane >= off) s += t;
    }
    if (lane == 63) ws[wv] = s;
    __syncthreads();
    if (tid == 0) { int a = 0; for (int q = 0; q < 4; ++q) { int t = ws[q]; ws[q] = a; a += t; } }
    __syncthreads();
    int ex = s - v + ws[wv];
    if (i < n) excl[i] = ex;
    if (tid == 255) bsum[blockIdx.x] = ex + v;
}

// phase 2: single-block scan of block sums (+ writes colptr[n] total)
__global__ void scan_bsums(const int* __restrict__ bsum, int* __restrict__ boff,
                           int nb, int* __restrict__ colptr, int n) {
    int tid = threadIdx.x, lane = tid & 63, wv = tid >> 6;
    __shared__ int ws[4];
    __shared__ int carry;
    if (tid == 0) carry = 0;
    __syncthreads();
    for (int base = 0; base < nb; base += 256) {
        int i = base + tid;
        int v = (i < nb) ? bsum[i] : 0;
        int s = v;
        #pragma unroll
        for (int off = 1; off < 64; off <<= 1) {
            int t = __shfl_up(s, off);
            if (lane >= off) s += t;
        }
        if (lane == 63) ws[wv] = s;
        __syncthreads();
        if (tid == 0) { int a = carry; for (int q = 0; q < 4; ++q) { int t = ws[q]; ws[q] = a; a += t; } carry = a; }
        __syncthreads();
        int ex = s - v + ws[wv];
        if (i < nb) boff[i] = ex;
        __syncthreads();
    }
    if (tid == 0) colptr[n] = carry;
}

// phase 3: add block offsets; also compute dinv
__global__ void scan_add_dinv(const int* __restrict__ excl, const int* __restrict__ boff,
                              const int* __restrict__ cnt, int* __restrict__ colptr,
                              float* __restrict__ dinv, int n) {
    int i = blockIdx.x * 256 + threadIdx.x;
    if (i < n) {
        colptr[i] = excl[i] + boff[blockIdx.x];
        dinv[i] = rsqrtf((float)cnt[i] + 1.0f);
    }
}

// XCD-partitioned atomic-free fill: 8 blocks per 256-edge chunk, block's part
// (blockIdx&7) filters cols into one contiguous node range -> scatter writes are
// XCD-local (perf heuristic only; ranks make slots unique under any mapping).
__global__ void fill_csr_part(const int* __restrict__ ei, const int* __restrict__ colptr,
                              const int* __restrict__ rank, int* __restrict__ esrc,
                              int E, int M, int psz, const int* __restrict__ flags) {
    int part = blockIdx.x & 7;
    int e = (blockIdx.x >> 3) * 256 + threadIdx.x;
    int lo = part * psz;
    int hi = lo + psz; if (hi > M) hi = M;
    if (e < E) {
        int r, c;
        if (flags[0]) { r = ei[2 * e]; c = ei[2 * E + 2 * e]; }
        else          { r = ei[e];     c = ei[E + e]; }
        if (c >= lo && c < hi && (unsigned)r < (unsigned)M) {
            int p = colptr[c] + rank[e];
            if ((unsigned)p < (unsigned)E) esrc[p] = r;
        }
    }
}

// ---------------- fused weight transposes f32 -> bf16 (W^T layout) ----------------
__global__ void transpose_all(const float* __restrict__ W1, const float* __restrict__ W2,
                              const float* __restrict__ W3,
                              unsigned short* __restrict__ Wt1, unsigned short* __restrict__ Wt2,
                              unsigned short* __restrict__ Wt3) {
    int i = blockIdx.x * 256 + threadIdx.x;
    if (i < 32768) {                       // W1: 128x256
        int k = i >> 8, n = i & 255;
        Wt1[n * 128 + k] = f2bf_bits(W1[i]);
    } else if (i < 32768 + 65536) {        // W2: 256x256
        int j = i - 32768;
        int k = j >> 8, n = j & 255;
        Wt2[n * 256 + k] = f2bf_bits(W2[j]);
    } else if (i < 114688) {               // W3: 256x64
        int j = i - 98304;
        int k = j >> 6, n = j & 63;
        Wt3[n * 256 + k] = f2bf_bits(W3[j]);
    }
}

// ---------------- x pre-scale: xs[i][k] = bf16(x[i][k] * dinv[i]) ----------------
__global__ void prescale_x(const float* __restrict__ x, const float* __restrict__ dinv,
                           unsigned short* __restrict__ xs, int total) {
    int i = blockIdx.x * 256 + threadIdx.x;
    if (i < total) {
        int row = i >> 7;   // K=128
        xs[i] = f2bf_bits(x[i] * dinv[row]);
    }
}

// ---------------- tiled GEMM (bf16 MFMA), K-split staging ----------------
// EPI=0: Y(bf16) = dinv[m] * (A·B)
// EPI=1: Y(bf16) = sigmoid(A·B + bias[n])
// EPI=2: Y(fp8 e4m3) = dinv[m] * (A·B)
template<int K, int BN, int NTOT, int EPI>
__global__ __launch_bounds__(256) void gemm_tile(
    const __bf16* __restrict__ A,
    const unsigned short* __restrict__ Bt,
    const float* __restrict__ dinv,
    const float* __restrict__ bias,
    void* __restrict__ Y,
    int M)
{
    constexpr int KS = (K > 128) ? 128 : K;   // staged chunk
    constexpr int KP = KS + 8;
    constexpr int NT = BN / 2 / 16;   // n-tiles per wave
    __shared__ unsigned short Bs[BN * KP];

    const int tid  = threadIdx.x;
    const int lane = tid & 63;
    const int wave = tid >> 6;        // 0..3
    const int wm   = wave >> 1;       // 0..1  row group
    const int wn   = wave & 1;        // 0..1  col group
    const int quad = lane >> 4;       // 0..3
    const int l16  = lane & 15;
    const int n0   = blockIdx.y * BN;

    int mrow[4];
#pragma unroll
    for (int mt = 0; mt < 4; ++mt) {
        int r = blockIdx.x * 128 + wm * 64 + mt * 16 + l16;
        mrow[mt] = (r < M) ? r : (M - 1);
    }

    f32x4_t acc[4][NT];
#pragma unroll
    for (int mt = 0; mt < 4; ++mt)
#pragma unroll
        for (int t = 0; t < NT; ++t) acc[mt][t] = (f32x4_t){0.f, 0.f, 0.f, 0.f};

    const unsigned short* BsW = &Bs[(wn * (BN / 2)) * KP];

    for (int kh = 0; kh < K; kh += KS) {
        constexpr int CH = BN * KS / 8;    // 16B chunks
        for (int idx = tid; idx < CH; idx += 256) {
            int n  = idx / (KS / 8);
            int k8 = idx - n * (KS / 8);
            uint4 v = *(const uint4*)(Bt + (size_t)(n0 + n) * K + kh + k8 * 8);
            *(uint4*)&Bs[n * KP + k8 * 8] = v;
        }
        __syncthreads();

#pragma unroll
        for (int kc = 0; kc < KS; kc += 32) {
            bf16x8_t a[4], b[NT];
#pragma unroll
            for (int mt = 0; mt < 4; ++mt)
                a[mt] = *(const bf16x8_t*)(A + (size_t)mrow[mt] * K + kh + kc + quad * 8);
#pragma unroll
            for (int t = 0; t < NT; ++t)
                b[t] = *(const bf16x8_t*)&BsW[(t * 16 + l16) * KP + kc + quad * 8];
#pragma unroll
            for (int mt = 0; mt < 4; ++mt)
#pragma unroll
                for (int t = 0; t < NT; ++t)
                    acc[mt][t] = __builtin_amdgcn_mfma_f32_16x16x32_bf16(a[mt], b[t], acc[mt][t], 0, 0, 0);
        }
        if (kh + KS < K) __syncthreads();
    }

    float bv[NT];
    if constexpr (EPI == 1) {
#pragma unroll
        for (int t = 0; t < NT; ++t)
            bv[t] = bias[n0 + wn * (BN / 2) + t * 16 + l16];
    }

#pragma unroll
    for (int mt = 0; mt < 4; ++mt) {
        int rowbase = blockIdx.x * 128 + wm * 64 + mt * 16 + quad * 4;
#pragma unroll
        for (int r = 0; r < 4; ++r) {
            int rrow = rowbase + r;
            if (rrow < M) {
                if constexpr (EPI == 0) {
                    float dv = dinv[rrow];
#pragma unroll
                    for (int t = 0; t < NT; ++t) {
                        int ccol = n0 + wn * (BN / 2) + t * 16 + l16;
                        ((__hip_bfloat16*)Y)[(size_t)rrow * NTOT + ccol] =
                            __float2bfloat16(acc[mt][t][r] * dv);
                    }
                } else if constexpr (EPI == 1) {
#pragma unroll
                    for (int t = 0; t < NT; ++t) {
                        int ccol = n0 + wn * (BN / 2) + t * 16 + l16;
                        float o = acc[mt][t][r] + bv[t];
                        o = 1.f / (1.f + __expf(-o));
                        ((__hip_bfloat16*)Y)[(size_t)rrow * NTOT + ccol] = __float2bfloat16(o);
                    }
                } else {
                    float dv = dinv[rrow];
#pragma unroll
                    for (int t = 0; t < NT; ++t) {
                        int ccol = n0 + wn * (BN / 2) + t * 16 + l16;
                        float o = acc[mt][t][r] * dv;
                        int pk = __builtin_amdgcn_cvt_pk_fp8_f32(o, o, 0, false);
                        ((unsigned char*)Y)[(size_t)rrow * NTOT + ccol] = (unsigned char)(pk & 0xff);
                    }
                }
            }
        }
    }
}

// ---------------- fp8 aggregation for C=256 (layer 2) ----------------
__global__ __launch_bounds__(256) void aggregate_fp8_256(
    const unsigned char* __restrict__ Y8,
    const int* __restrict__ colptr,
    const int* __restrict__ esrc,
    const float* __restrict__ dinv,
    const float* __restrict__ bias,
    unsigned short* __restrict__ H,
    int M, int Etot)
{
    const int lane = threadIdx.x & 63;
    const int wave = threadIdx.x >> 6;
    const int l = lane & 15;       // 16B sub-offset
    const int g = lane >> 4;       // 0..3 edge group
    int node = blockIdx.x * 4 + wave;
    if (node >= M) return;

    int s = colptr[node];
    int e = colptr[node + 1];
    if (s < 0) s = 0;
    if (e > Etot) e = Etot;
    if (e < s) e = s;

    const char* Yb = (const char*)Y8;
    const unsigned loff = (unsigned)(l * 16);

    float acc[16];
    #pragma unroll
    for (int k = 0; k < 16; ++k) acc[k] = 0.f;

    auto unpack = [&](uint4 u) {
        auto p0 = __builtin_amdgcn_cvt_pk_f32_fp8(u.x, false);
        auto p1 = __builtin_amdgcn_cvt_pk_f32_fp8(u.x, true);
        auto p2 = __builtin_amdgcn_cvt_pk_f32_fp8(u.y, false);
        auto p3 = __builtin_amdgcn_cvt_pk_f32_fp8(u.y, true);
        auto p4 = __builtin_amdgcn_cvt_pk_f32_fp8(u.z, false);
        auto p5 = __builtin_amdgcn_cvt_pk_f32_fp8(u.z, true);
        auto p6 = __builtin_amdgcn_cvt_pk_f32_fp8(u.w, false);
        auto p7 = __builtin_amdgcn_cvt_pk_f32_fp8(u.w, true);
        acc[0]  += p0[0]; acc[1]  += p0[1];
        acc[2]  += p1[0]; acc[3]  += p1[1];
        acc[4]  += p2[0]; acc[5]  += p2[1];
        acc[6]  += p3[0]; acc[7]  += p3[1];
        acc[8]  += p4[0]; acc[9]  += p4[1];
        acc[10] += p5[0]; acc[11] += p5[1];
        acc[12] += p6[0]; acc[13] += p6[1];
        acc[14] += p7[0]; acc[15] += p7[1];
    };

    for (int base = s; base < e; base += 64) {
        int n = e - base; if (n > 64) n = 64;
        unsigned myOff = 0;
        if (lane < n) myOff = (unsigned)esrc[base + lane] << 8;   // 256B rows
        int j = 0;
        #pragma unroll 2
        for (; j + 4 <= n; j += 4) {
            unsigned off = __shfl(myOff, j + g) + loff;
            uint4 u = *(const uint4*)(Yb + off);
            unpack(u);
        }
        if (j < n) {
            unsigned off = __shfl(myOff, j + g) + loff;
            if (j + g < n) {
                uint4 u = *(const uint4*)(Yb + off);
                unpack(u);
            }
        }
    }
    if (g == 0) {
        uint4 u = *(const uint4*)(Yb + ((unsigned)node << 8) + loff);
        unpack(u);
    }
    #pragma unroll
    for (int off = 16; off < 64; off <<= 1) {
        #pragma unroll
        for (int k = 0; k < 16; ++k) acc[k] += __shfl_xor(acc[k], off);
    }

    if (g == 0) {   // lanes 0..15 hold channels [l*16, l*16+16)
        float dv = dinv[node];
        float o[16];
        #pragma unroll
        for (int k = 0; k < 16; ++k) {
            o[k] = acc[k] * dv + bias[l * 16 + k];
            o[k] = 1.f / (1.f + __expf(-o[k]));
        }
        uint4 s0, s1;
        s0.x = (unsigned)f2bf_bits(o[0])  | ((unsigned)f2bf_bits(o[1])  << 16);
        s0.y = (unsigned)f2bf_bits(o[2])  | ((unsigned)f2bf_bits(o[3])  << 16);
        s0.z = (unsigned)f2bf_bits(o[4])  | ((unsigned)f2bf_bits(o[5])  << 16);
        s0.w = (unsigned)f2bf_bits(o[6])  | ((unsigned)f2bf_bits(o[7])  << 16);
        s1.x = (unsigned)f2bf_bits(o[8])  | ((unsigned)f2bf_bits(o[9])  << 16);
        s1.y = (unsigned)f2bf_bits(o[10]) | ((unsigned)f2bf_bits(o[11]) << 16);
        s1.z = (unsigned)f2bf_bits(o[12]) | ((unsigned)f2bf_bits(o[13]) << 16);
        s1.w = (unsigned)f2bf_bits(o[14]) | ((unsigned)f2bf_bits(o[15]) << 16);
        unsigned short* Hp = H + (size_t)node * 256 + l * 16;
        *(uint4*)Hp       = s0;
        *(uint4*)(Hp + 8) = s1;
    }
}

// ---------------- bf16 monolithic aggregation (layers 1 & 3) ----------------
template<int C, bool SIG, bool OUTF32, bool HASB>
__global__ __launch_bounds__(256) void aggregate2(
    const unsigned short* __restrict__ Y,
    const int* __restrict__ colptr,
    const int* __restrict__ esrc,
    const float* __restrict__ dinv,
    const float* __restrict__ bias,
    void* __restrict__ H,
    int M, int Etot)
{
    constexpr int G   = C / 8;       // 128->16, 64->8
    constexpr int EPW = 64 / G;      // 4, 8
    const int lane = threadIdx.x & 63;
    const int wave = threadIdx.x >> 6;
    const int l = lane & (G - 1);
    const int g = lane / G;
    int node = blockIdx.x * 4 + wave;
    if (node >= M) return;

    int s = colptr[node];
    int e = colptr[node + 1];
    if (s < 0) s = 0;
    if (e > Etot) e = Etot;
    if (e < s) e = s;

    const char* Yb = (const char*)Y;
    const unsigned loff = (unsigned)(l * 16);

    float acc[8];
    #pragma unroll
    for (int k = 0; k < 8; ++k) acc[k] = 0.f;

    auto unpack = [&](uint4 u) {
        acc[0] += bits2f(u.x << 16);
        acc[1] += bits2f(u.x & 0xffff0000u);
        acc[2] += bits2f(u.y << 16);
        acc[3] += bits2f(u.y & 0xffff0000u);
        acc[4] += bits2f(u.z << 16);
        acc[5] += bits2f(u.z & 0xffff0000u);
        acc[6] += bits2f(u.w << 16);
        acc[7] += bits2f(u.w & 0xffff0000u);
    };

    for (int base = s; base < e; base += 64) {
        int n = e - base; if (n > 64) n = 64;
        unsigned myOff = 0;
        if (lane < n) myOff = (unsigned)esrc[base + lane] * (unsigned)(C * 2);
        int j = 0;
        #pragma unroll 2
        for (; j + EPW <= n; j += EPW) {
            unsigned off = __shfl(myOff, j + g) + loff;
            uint4 u = *(const uint4*)(Yb + off);
            unpack(u);
        }
        if (j < n) {
            unsigned off = __shfl(myOff, j + g) + loff;
            if (j + g < n) {
                uint4 u = *(const uint4*)(Yb + off);
                unpack(u);
            }
        }
    }
    if (g == 0) {
        unsigned off = (unsigned)node * (unsigned)(C * 2) + loff;
        uint4 u = *(const uint4*)(Yb + off);
        unpack(u);
    }
    #pragma unroll
    for (int off = G; off < 64; off <<= 1) {
        #pragma unroll
        for (int k = 0; k < 8; ++k) acc[k] += __shfl_xor(acc[k], off);
    }

    if (g == 0) {
        float dv = dinv[node];
        float o[8];
        #pragma unroll
        for (int k = 0; k < 8; ++k) {
            o[k] = acc[k] * dv;
            if (HASB) o[k] += bias[l * 8 + k];
            if (SIG) o[k] = 1.f / (1.f + __expf(-o[k]));
        }
        if constexpr (OUTF32) {
            float* Hp = (float*)H + (size_t)node * C + l * 8;
            *(float4*)Hp       = (float4){o[0], o[1], o[2], o[3]};
            *(float4*)(Hp + 4) = (float4){o[4], o[5], o[6], o[7]};
        } else {
            uint4 st;
            st.x = (unsigned)f2bf_bits(o[0]) | ((unsigned)f2bf_bits(o[1]) << 16);
            st.y = (unsigned)f2bf_bits(o[2]) | ((unsigned)f2bf_bits(o[3]) << 16);
            st.z = (unsigned)f2bf_bits(o[4]) | ((unsigned)f2bf_bits(o[5]) << 16);
            st.w = (unsigned)f2bf_bits(o[6]) | ((unsigned)f2bf_bits(o[7]) << 16);
            *(uint4*)((unsigned short*)H + (size_t)node * C + l * 8) = st;
        }
    }
}

// ---------------- launch ----------------

extern "C" void kernel_launch(void* const* d_in, const int* in_sizes, int n_in,
                              void* d_out, int out_size, void* d_ws, size_t ws_size,
                              hipStream_t stream)
{
    int iEI = 2, iW1 = 3, iB1 = 4, iW2 = 5, iB2 = 6, iW3 = 7, iB3 = 8;
    if (n_in == 8) { iEI = 1; iW1 = 2; iB1 = 3; iW2 = 4; iB2 = 5; iW3 = 6; iB3 = 7; }

    const float* x  = (const float*)d_in[0];
    const int* ei   = (const int*)d_in[iEI];
    const float* W1 = (const float*)d_in[iW1];
    const float* b1 = (const float*)d_in[iB1];
    const float* W2 = (const float*)d_in[iW2];
    const float* b2 = (const float*)d_in[iB2];
    const float* W3 = (const float*)d_in[iW3];
    const float* b3 = (const float*)d_in[iB3];

    const int M = in_sizes[0] / 128;     // 50000
    const int E = in_sizes[iEI] / 2;     // 800000
    const int NB = (M + 255) / 256;      // scan blocks
    const int PSZ = (M + 7) / 8;         // nodes per fill partition

    auto rnd = [](size_t b) { return (b + 255) & ~(size_t)255; };
    size_t needed = rnd(64 * 4)                          // flags
                  + rnd((size_t)M * 4) * 2               // dinv, cnt
                  + rnd((size_t)(M + 1) * 4)             // colptr
                  + rnd((size_t)M * 4)                   // excl
                  + rnd((size_t)(NB + 1) * 4) * 2        // bsum, boff
                  + rnd((size_t)E * 4) * 2               // esrc, rank
                  + rnd((size_t)256 * 128 * 2)           // Wt1
                  + rnd((size_t)256 * 256 * 2)           // Wt2
                  + rnd((size_t)64 * 256 * 2)            // Wt3
                  + rnd((size_t)M * 256 * 2) * 2;        // ybuf, hbuf
    if (ws_size < needed) {
        sentinel_fill<<<(out_size + 255) / 256, 256, 0, stream>>>((float*)d_out, out_size);
        return;
    }

    char* p = (char*)d_ws;
    auto alloc = [&](size_t bytes) {
        char* r = p;
        p += (bytes + 255) & ~(size_t)255;
        return r;
    };
    int* flags  = (int*)alloc(64 * 4);
    float* dinv = (float*)alloc((size_t)M * 4);
    int* cnt    = (int*)alloc((size_t)M * 4);
    int* colptr = (int*)alloc((size_t)(M + 1) * 4);
    int* excl   = (int*)alloc((size_t)M * 4);
    int* bsum   = (int*)alloc((size_t)(NB + 1) * 4);
    int* boff   = (int*)alloc((size_t)(NB + 1) * 4);
    int* esrc   = (int*)alloc((size_t)E * 4);
    int* rank   = (int*)alloc((size_t)E * 4);
    unsigned short* Wt1 = (unsigned short*)alloc((size_t)256 * 128 * 2);
    unsigned short* Wt2 = (unsigned short*)alloc((size_t)256 * 256 * 2);
    unsigned short* Wt3 = (unsigned short*)alloc((size_t)64 * 256 * 2);
    __hip_bfloat16* ybuf = (__hip_bfloat16*)alloc((size_t)M * 256 * 2);
    __hip_bfloat16* hbuf = (__hip_bfloat16*)alloc((size_t)M * 256 * 2);

    // region reuse inside ybuf:
    unsigned short* xs = (unsigned short*)ybuf;                    // M x 128 bf16
    unsigned short* xa = (unsigned short*)ybuf + (size_t)M * 128;  // M x 128 bf16
    unsigned char*  y8 = (unsigned char*)ybuf;                     // M x 256 fp8 (after xs dead)

    detect_ei<<<1, 64, 0, stream>>>((const unsigned int*)ei, flags);

    hipMemsetAsync(cnt, 0, (size_t)M * 4, stream);
    count_rank_dual<<<(E + 255) / 256, 256, 0, stream>>>(ei, cnt, rank, E, M, flags);
    scan_blocks<<<NB, 256, 0, stream>>>(cnt, excl, bsum, M);
    scan_bsums<<<1, 256, 0, stream>>>(bsum, boff, NB, colptr, M);
    scan_add_dinv<<<NB, 256, 0, stream>>>(excl, boff, cnt, colptr, dinv, M);
    fill_csr_part<<<((E + 255) / 256) * 8, 256, 0, stream>>>(
        ei, colptr, rank, esrc, E, M, PSZ, flags);
    transpose_all<<<(114688 + 255) / 256, 256, 0, stream>>>(W1, W2, W3, Wt1, Wt2, Wt3);

    int gmb = (M + 127) / 128;           // 391
    int ga  = (M + 3) / 4;               // 12500

    // Layer 1: aggregate x first (S·x), then GEMM with fused bias+sigmoid
    prescale_x<<<((M * 128) + 255) / 256, 256, 0, stream>>>(x, dinv, xs, M * 128);
    aggregate2<128, false, false, false><<<ga, 256, 0, stream>>>(
        xs, colptr, esrc, dinv, nullptr, xa, M, E);
    gemm_tile<128, 128, 256, 1><<<dim3(gmb, 2), 256, 0, stream>>>(
        (const __bf16*)xa, Wt1, dinv, b1, hbuf, M);
    // Layer 2: GEMM -> fp8 table, fp8 gather aggregate -> bf16 h2
    gemm_tile<256, 128, 256, 2><<<dim3(gmb, 2), 256, 0, stream>>>(
        (const __bf16*)hbuf, Wt2, dinv, b2, y8, M);
    aggregate_fp8_256<<<ga, 256, 0, stream>>>(
        y8, colptr, esrc, dinv, b2, (unsigned short*)hbuf, M, E);
    // Layer 3: bf16
    gemm_tile<256, 64, 64, 0><<<dim3(gmb, 1), 256, 0, stream>>>(
        (const __bf16*)hbuf, Wt3, dinv, b3, ybuf, M);
    aggregate2<64, false, true, true><<<ga, 256, 0, stream>>>(
        (const unsigned short*)ybuf, colptr, esrc, dinv, b3, d_out, M, E);
}